// Round 1
// baseline (140.623 us; speedup 1.0000x reference)
//
#include <hip/hip_runtime.h>

typedef __attribute__((ext_vector_type(8))) short short8;
typedef __attribute__((ext_vector_type(16))) float f32x16;

#define DEVFN static __device__ __forceinline__

DEVFN float bf2f(unsigned short u){
  union { unsigned int i; float f; } v; v.i = ((unsigned int)u) << 16; return v.f;
}
// round-to-nearest-even f32 -> bf16 (finite inputs only)
DEVFN unsigned short f2bf(float f){
  unsigned int u = __float_as_uint(f);
  unsigned int r = u + 0x7FFFu + ((u >> 16) & 1u);
  return (unsigned short)(r >> 16);
}
DEVFN float tanh_fast(float x){
  // tanh(x) = 1 - 2/(e^{2x}+1); exp2 hardware transcendental
  float t = __builtin_amdgcn_exp2f(x * 2.885390081777926815f);
  return 1.0f - 2.0f * __builtin_amdgcn_rcpf(t + 1.0f);
}
DEVFN void gl_lds16(const unsigned short* g, unsigned short* l){
  __builtin_amdgcn_global_load_lds(
      (const __attribute__((address_space(1))) void*)g,
      (__attribute__((address_space(3))) void*)l, 16, 0, 0);
}
// shared A/B K-slot mapping for 32x32x16 MFMA: lane half h=lane>>5, elem j in [0,8)
DEVFN int kmap(int h, int j){ return 4*h + (j & 3) + 8*(j >> 2); }

// ---------------- weight bake kernels ----------------
// wfrag layout (halfwords): (((i*4 + c)*4 + nt)*64 + lane)*8 + j ; i=(l*64+f)
__global__ void bake_w0(const float* __restrict__ wx0, const float* __restrict__ wy0,
                        unsigned short* __restrict__ wfrag){
  int slot = blockIdx.x * 256 + threadIdx.x;      // < 196608
  int lane = slot & 63;
  int q = slot >> 6;
  int nt = q & 3; q >>= 2;
  int c  = q & 3; q >>= 2;
  int i  = q;
  int l = i >> 6, f = i & 63;
  int n = nt * 32 + (lane & 31);
  int h = lane >> 5;
  const float* w = (n < 64) ? wx0 : wy0;
  int k = n & 63;
  unsigned int pk[4];
#pragma unroll
  for (int jj = 0; jj < 4; ++jj){
    int g0 = c*16 + kmap(h, 2*jj);
    int g1 = c*16 + kmap(h, 2*jj + 1);
    unsigned int b0 = f2bf(w[((k*64 + f)*64 + g0)*3 + l]);
    unsigned int b1 = f2bf(w[((k*64 + f)*64 + g1)*3 + l]);
    pk[jj] = b0 | (b1 << 16);
  }
  *reinterpret_cast<uint4*>(wfrag + (size_t)slot * 8) = make_uint4(pk[0], pk[1], pk[2], pk[3]);
}

// whfrag: ((((layer*2+path)*4 + c)*2 + nt)*64 + lane)*8 + j
__global__ void bake_wh(const float* __restrict__ wxh, const float* __restrict__ wyh,
                        unsigned short* __restrict__ whfrag){
  int slot = blockIdx.x * 256 + threadIdx.x;      // < 2048
  int lane = slot & 63;
  int q = slot >> 6;
  int nt = q & 1; q >>= 1;
  int c  = q & 3; q >>= 2;
  int path = q & 1; int layer = q >> 1;
  const float* w = path ? wyh : wxh;
  int n = nt*32 + (lane & 31);
  int h = lane >> 5;
  unsigned int pk[4];
#pragma unroll
  for (int jj = 0; jj < 4; ++jj){
    int k0 = c*16 + kmap(h, 2*jj);
    int k1 = c*16 + kmap(h, 2*jj + 1);
    unsigned int b0 = f2bf(w[layer*4096 + k0*64 + n]);
    unsigned int b1 = f2bf(w[layer*4096 + k1*64 + n]);
    pk[jj] = b0 | (b1 << 16);
  }
  *reinterpret_cast<uint4*>(whfrag + (size_t)slot * 8) = make_uint4(pk[0], pk[1], pk[2], pk[3]);
}

// wffrag: (((path*4 + c)*6 + ntf)*64 + lane)*8 + j ; n = ntf*32+(lane&31) = l*64+f
__global__ void bake_wf(const float* __restrict__ wxf, const float* __restrict__ wyf,
                        unsigned short* __restrict__ wffrag){
  int slot = blockIdx.x * 256 + threadIdx.x;      // < 3072
  int lane = slot & 63;
  int q = slot >> 6;            // < 48
  int ntf = q % 6;
  int q2 = q / 6;
  int c = q2 & 3; int path = q2 >> 2;
  const float* w = path ? wyf : wxf;
  int n = ntf*32 + (lane & 31);
  int lw = n >> 6, fw = n & 63;
  int h = lane >> 5;
  unsigned int pk[4];
#pragma unroll
  for (int jj = 0; jj < 4; ++jj){
    int k0 = c*16 + kmap(h, 2*jj);
    int k1 = c*16 + kmap(h, 2*jj + 1);
    unsigned int b0 = f2bf(w[(lw*64 + fw)*64 + k0]);
    unsigned int b1 = f2bf(w[(lw*64 + fw)*64 + k1]);
    pk[jj] = b0 | (b1 << 16);
  }
  *reinterpret_cast<uint4*>(wffrag + (size_t)slot * 8) = make_uint4(pk[0], pk[1], pk[2], pk[3]);
}

// ---------------- main fused GEMM: mix[p][0:64]=mix_x, [64:128]=mix_y ----------------
// LDS map (bytes): xg_t[32][9][68]bf16 @0 (39168) ; y_t @39168 (39168) ;
//                  A_img[4][64][8]bf16 @78336 (4096) ; wbuf[2][8192]bf16 @82432 (32768)
//                  red (reduce, reuse @0, 49152)
__global__ __launch_bounds__(512, 1)
void gemm_mix(const float* __restrict__ x, const float* __restrict__ y,
              const unsigned short* __restrict__ wfrag, float* __restrict__ mix){
  extern __shared__ char lds[];
  unsigned short* xg_t  = (unsigned short*)lds;
  unsigned short* y_t   = (unsigned short*)(lds + 39168);
  unsigned short* A_img = (unsigned short*)(lds + 78336);
  unsigned short* wbuf  = (unsigned short*)(lds + 82432);
  float* red = (float*)lds;

  const int t = threadIdx.x;
  const long pbase = (long)blockIdx.x * 32;

  // prestage W tile for iter 0 (16KB = 2 x 8KB rounds)
  gl_lds16(wfrag + t*8,        wbuf + t*8);
  gl_lds16(wfrag + 4096 + t*8, wbuf + 4096 + t*8);

  // stage points: gate, xg=x*gate, y  (bf16, transposed [p][s][feat])
#pragma unroll
  for (int rep = 0; rep < 4; ++rep){
    int idx = t + rep*512;
    int p = idx >> 6, fq = idx & 63;
    const float* xr = x + ((pbase + p)*64 + fq)*9;
    const float* yr = y + ((pbase + p)*64 + fq)*9;
    float xv[9], yv[9];
#pragma unroll
    for (int s = 0; s < 9; ++s){ xv[s] = xr[s]; yv[s] = yr[s]; }
    float c0 = xv[2]*yv[3] - xv[3]*yv[2];
    float c1 = xv[3]*yv[1] - xv[1]*yv[3];
    float c2 = xv[1]*yv[2] - xv[2]*yv[1];
    float gate = c0*yv[0] + c1*yv[1] + c2*yv[2];
    int rb = p*9;
#pragma unroll
    for (int s = 0; s < 9; ++s){
      xg_t[(rb + s)*68 + fq] = f2bf(xv[s]*gate);
      y_t [(rb + s)*68 + fq] = f2bf(yv[s]);
    }
  }
  __syncthreads();

  // A-gen assignment: slot=(c,lane), two threads per slot (halves)
  const int slot = t >> 1, half = t & 1;
  const int alane = slot & 63, ac = slot >> 6;
  const int ap = alane & 31, ah = alane >> 5;
  const int g0 = ac*16 + 4*ah + 8*half;          // 4 consecutive g
  const int awoff = (ac*64 + alane)*8 + half*4;

  // MFMA assignment: wave w -> (n-half nw, K-chunk wc)
  const int w = t >> 6, lane = t & 63;
  const int nw = w & 1, wc = w >> 1;
  const int aroff = (wc*64 + lane)*8;

  f32x16 acc0, acc1;
#pragma unroll
  for (int r = 0; r < 16; ++r){ acc0[r] = 0.f; acc1[r] = 0.f; }

#pragma unroll 1
  for (int i = 0; i < 192; ++i){
    const int l = i >> 6, f = i & 63;
    // ---- generate A tile (32p x 64g) for fixed (l,f), frag-order image ----
    {
      float a0=0.f, a1=0.f, a2=0.f, a3=0.f;
#define ABODY(S) { int ro = (ap*9 + (S))*68; \
      float yv = bf2f(y_t[ro + f]); \
      ushort4 xv = *(const ushort4*)&xg_t[ro + g0]; \
      a0 += yv*bf2f(xv.x); a1 += yv*bf2f(xv.y); \
      a2 += yv*bf2f(xv.z); a3 += yv*bf2f(xv.w); }
      if (l == 0){ ABODY(0) }
      else if (l == 1){ ABODY(1) ABODY(2) ABODY(3) }
      else { ABODY(4) ABODY(5) ABODY(6) ABODY(7) ABODY(8) }
#undef ABODY
      ushort4 o;
      o.x = f2bf(a0); o.y = f2bf(a1); o.z = f2bf(a2); o.w = f2bf(a3);
      *(ushort4*)&A_img[awoff] = o;
    }
    // ---- stage W[i+1]; counted vmcnt keeps prefetch in flight ----
    if (i < 191){
      const unsigned short* src = wfrag + (size_t)(i + 1) * 8192;
      unsigned short* dst = wbuf + ((i + 1) & 1) * 8192;
      gl_lds16(src + t*8,        dst + t*8);
      gl_lds16(src + 4096 + t*8, dst + 4096 + t*8);
      asm volatile("s_waitcnt vmcnt(2)" ::: "memory");
    } else {
      asm volatile("s_waitcnt vmcnt(0)" ::: "memory");
    }
    asm volatile("s_waitcnt lgkmcnt(0)" ::: "memory");
    __builtin_amdgcn_sched_barrier(0);
    __builtin_amdgcn_s_barrier();
    // ---- MFMA: 2 n-tiles for this wave's chunk ----
    {
      const unsigned short* wb = wbuf + (i & 1)*8192 + (wc*4 + nw*2)*512 + lane*8;
      short8 av = *(const short8*)&A_img[aroff];
      short8 b0 = *(const short8*)wb;
      short8 b1 = *(const short8*)(wb + 512);
      acc0 = __builtin_amdgcn_mfma_f32_32x32x16_bf16(av, b0, acc0, 0, 0, 0);
      acc1 = __builtin_amdgcn_mfma_f32_32x32x16_bf16(av, b1, acc1, 0, 0, 0);
    }
    __builtin_amdgcn_sched_barrier(0);
    __builtin_amdgcn_s_barrier();
  }

  // ---- reduce over the 4 chunk-waves, write mix ----
  if (wc > 0){
    float* dst = red + ((wc - 1)*2 + nw)*2048 + lane*16;
#pragma unroll
    for (int r = 0; r < 16; ++r) dst[r] = acc0[r];
#pragma unroll
    for (int r = 0; r < 16; ++r) dst[1024 + r] = acc1[r];
  }
  __syncthreads();
  if (wc == 0){
#pragma unroll
    for (int cc = 0; cc < 3; ++cc){
      const float* sp = red + (cc*2 + nw)*2048 + lane*16;
#pragma unroll
      for (int r = 0; r < 16; ++r){ acc0[r] += sp[r]; acc1[r] += sp[1024 + r]; }
    }
    const int col = lane & 31, hh = lane >> 5;
#pragma unroll
    for (int r = 0; r < 16; ++r){
      int p = (r & 3) + 8*(r >> 2) + 4*hh;     // verified C/D row map (m101)
      float* mr = mix + (pbase + p)*128 + nw*64;
      mr[col] = acc0[r];
      mr[32 + col] = acc1[r];
    }
  }
}

// ---------------- MLP + final einsum + epilogue ----------------
// LDS halfword map: act[path][buf][32][68] @ (path*2+buf)*2176 ; ox @8704 [32][196] ; oy @14976
__global__ __launch_bounds__(256, 1)
void mlp_final(const float* __restrict__ x, const float* __restrict__ y,
               const unsigned short* __restrict__ whfrag,
               const unsigned short* __restrict__ wffrag,
               const float* __restrict__ mix, float* __restrict__ out){
  extern __shared__ char ldsm[];
  unsigned short* hw = (unsigned short*)ldsm;
  const int t = threadIdx.x;
  const long pbase = (long)blockIdx.x * 32;

  {  // load mix -> act buf0 (bf16)
    int p = t >> 3, n0 = (t & 7) * 16;
    const float* src = mix + (pbase + p)*128 + n0;
    int path = n0 >> 6, nn = n0 & 63;
    unsigned short* dst = hw + (path*2)*2176 + p*68 + nn;
#pragma unroll
    for (int q2 = 0; q2 < 16; ++q2) dst[q2] = f2bf(src[q2]);
  }
  __syncthreads();

  const int w = t >> 6, lane = t & 63;
  const int path = w >> 1, ntw = w & 1;
  const int prow = lane & 31, h = lane >> 5;
  int cur = 0;

#pragma unroll
  for (int layer = 0; layer < 2; ++layer){
    const unsigned short* act = hw + (path*2 + cur)*2176;
    f32x16 acc;
#pragma unroll
    for (int r = 0; r < 16; ++r) acc[r] = 0.f;
#pragma unroll
    for (int c = 0; c < 4; ++c){
      int ab = prow*68 + c*16 + 4*h;
      ushort4 lo = *(const ushort4*)&act[ab];
      ushort4 hi = *(const ushort4*)&act[ab + 8];
      short8 av; av[0]=lo.x; av[1]=lo.y; av[2]=lo.z; av[3]=lo.w;
      av[4]=hi.x; av[5]=hi.y; av[6]=hi.z; av[7]=hi.w;
      short8 bv = *(const short8*)(whfrag + ((((layer*2 + path)*4 + c)*2 + ntw)*512 + lane*8));
      acc = __builtin_amdgcn_mfma_f32_32x32x16_bf16(av, bv, acc, 0, 0, 0);
    }
    unsigned short* nact = hw + (path*2 + (cur ^ 1))*2176;
#pragma unroll
    for (int r = 0; r < 16; ++r){
      int p = (r & 3) + 8*(r >> 2) + 4*h;
      nact[p*68 + ntw*32 + prow] = f2bf(tanh_fast(acc[r]));
    }
    cur ^= 1;
    __syncthreads();
  }

  {  // final einsum: o[p][n=l*64+f], N=192 -> each wave 3 n-tiles
    const unsigned short* act = hw + (path*2 + cur)*2176;
    unsigned short* ob = hw + 8704 + path*6272;
#pragma unroll
    for (int e = 0; e < 3; ++e){
      int ntf = ntw*3 + e;
      f32x16 acc;
#pragma unroll
      for (int r = 0; r < 16; ++r) acc[r] = 0.f;
#pragma unroll
      for (int c = 0; c < 4; ++c){
        int ab = prow*68 + c*16 + 4*h;
        ushort4 lo = *(const ushort4*)&act[ab];
        ushort4 hi = *(const ushort4*)&act[ab + 8];
        short8 av; av[0]=lo.x; av[1]=lo.y; av[2]=lo.z; av[3]=lo.w;
        av[4]=hi.x; av[5]=hi.y; av[6]=hi.z; av[7]=hi.w;
        short8 bv = *(const short8*)(wffrag + (((path*4 + c)*6 + ntf)*512 + lane*8));
        acc = __builtin_amdgcn_mfma_f32_32x32x16_bf16(av, bv, acc, 0, 0, 0);
      }
#pragma unroll
      for (int r = 0; r < 16; ++r){
        int p = (r & 3) + 8*(r >> 2) + 4*h;
        ob[p*196 + ntf*32 + prow] = f2bf(tanh_fast(acc[r]));
      }
    }
  }
  __syncthreads();

  const unsigned short* oxb = hw + 8704;
  const unsigned short* oyb = hw + 8704 + 6272;
#pragma unroll 1
  for (int rep = 0; rep < 8; ++rep){
    int idx = t + rep*256;
    int p = idx >> 6, fq = idx & 63;
    const float* xr = x + ((pbase + p)*64 + fq)*9;
    const float* yr = y + ((pbase + p)*64 + fq)*9;
    float xv[9], yv[9];
#pragma unroll
    for (int s = 0; s < 9; ++s){ xv[s] = xr[s]; yv[s] = yr[s]; }
    float c0 = xv[2]*yv[3] - xv[3]*yv[2];
    float c1 = xv[3]*yv[1] - xv[1]*yv[3];
    float c2 = xv[1]*yv[2] - xv[2]*yv[1];
    float gate = c0*yv[0] + c1*yv[1] + c2*yv[2];
    float ox0 = bf2f(oxb[p*196 + fq]);
    float ox1 = bf2f(oxb[p*196 + 64 + fq]);
    float ox2 = bf2f(oxb[p*196 + 128 + fq]);
    float oy0 = bf2f(oyb[p*196 + fq]);
    float oy1 = bf2f(oyb[p*196 + 64 + fq]);
    float oy2 = bf2f(oyb[p*196 + 128 + fq]);
    float* orow = out + ((pbase + p)*64 + fq)*9;
    orow[0] = ox0*xv[0]*gate + oy0*yv[0];
#pragma unroll
    for (int s = 1; s < 4; ++s) orow[s] = ox1*xv[s]*gate + oy1*yv[s];
#pragma unroll
    for (int s = 4; s < 9; ++s) orow[s] = ox2*xv[s]*gate + oy2*yv[s];
  }
}

extern "C" void kernel_launch(void* const* d_in, const int* in_sizes, int n_in,
                              void* d_out, int out_size, void* d_ws, size_t ws_size,
                              hipStream_t stream){
  (void)in_sizes; (void)n_in; (void)out_size; (void)ws_size;
  const float* x   = (const float*)d_in[0];
  const float* y   = (const float*)d_in[1];
  const float* wx0 = (const float*)d_in[2];
  const float* wy0 = (const float*)d_in[3];
  const float* wxh = (const float*)d_in[4];
  const float* wyh = (const float*)d_in[5];
  const float* wxf = (const float*)d_in[6];
  const float* wyf = (const float*)d_in[7];
  float* out = (float*)d_out;
  char* ws = (char*)d_ws;
  unsigned short* wfrag  = (unsigned short*)(ws);             // 3,145,728 B
  unsigned short* whfrag = (unsigned short*)(ws + 3145728);   //    32,768 B
  unsigned short* wffrag = (unsigned short*)(ws + 3178496);   //    49,152 B
  float* mix = (float*)(ws + 3227648);                        // 4,194,304 B

  (void)hipFuncSetAttribute((const void*)gemm_mix,
        hipFuncAttributeMaxDynamicSharedMemorySize, 115200);
  (void)hipFuncSetAttribute((const void*)mlp_final,
        hipFuncAttributeMaxDynamicSharedMemorySize, 43520);

  hipLaunchKernelGGL(bake_w0, dim3(768), dim3(256), 0, stream, wx0, wy0, wfrag);
  hipLaunchKernelGGL(bake_wh, dim3(8),   dim3(256), 0, stream, wxh, wyh, whfrag);
  hipLaunchKernelGGL(bake_wf, dim3(12),  dim3(256), 0, stream, wxf, wyf, wffrag);
  hipLaunchKernelGGL(gemm_mix, dim3(256), dim3(512), 115200, stream, x, y, wfrag, mix);
  hipLaunchKernelGGL(mlp_final, dim3(256), dim3(256), 42496, stream, x, y, whfrag, wffrag, mix, out);
}

// Round 2
// 117.921 us; speedup vs baseline: 1.1925x; 1.1925x over previous
//
#include <hip/hip_runtime.h>
#include <hip/hip_bf16.h>

typedef __attribute__((ext_vector_type(8))) short short8;
typedef __attribute__((ext_vector_type(16))) float f32x16;

#define DEVFN static __device__ __forceinline__

DEVFN float bf2f(unsigned short u){
  union { unsigned int i; float f; } v; v.i = ((unsigned int)u) << 16; return v.f;
}
DEVFN unsigned short f2bf(float f){
  unsigned int u = __float_as_uint(f);
  unsigned int r = u + 0x7FFFu + ((u >> 16) & 1u);
  return (unsigned short)(r >> 16);
}
DEVFN unsigned int pkbf(float lo, float hi){
  __hip_bfloat162 h = __float22bfloat162_rn(make_float2(lo, hi));
  return *reinterpret_cast<unsigned int*>(&h);
}
DEVFN float tanh_fast(float x){
  float t = __builtin_amdgcn_exp2f(x * 2.885390081777926815f);
  return 1.0f - 2.0f * __builtin_amdgcn_rcpf(t + 1.0f);
}
DEVFN void gl_lds16(const unsigned short* g, unsigned short* l){
  __builtin_amdgcn_global_load_lds(
      (const __attribute__((address_space(1))) void*)g,
      (__attribute__((address_space(3))) void*)l, 16, 0, 0);
}
// shared A/B K-slot mapping for 32x32x16 MFMA fragments
DEVFN int kmap(int h, int j){ return 4*h + (j & 3) + 8*(j >> 2); }

// ---------------- weight bake kernels (unchanged layouts) ----------------
// wfrag (halfwords): (((i*4 + c)*4 + nt)*64 + lane)*8 + j ; i=(l*64+f)
__global__ void bake_w0(const float* __restrict__ wx0, const float* __restrict__ wy0,
                        unsigned short* __restrict__ wfrag){
  int slot = blockIdx.x * 256 + threadIdx.x;      // < 196608
  int lane = slot & 63;
  int q = slot >> 6;
  int nt = q & 3; q >>= 2;
  int c  = q & 3; q >>= 2;
  int i  = q;
  int l = i >> 6, f = i & 63;
  int n = nt * 32 + (lane & 31);
  int h = lane >> 5;
  const float* w = (n < 64) ? wx0 : wy0;
  int k = n & 63;
  unsigned int pk[4];
#pragma unroll
  for (int jj = 0; jj < 4; ++jj){
    int g0 = c*16 + kmap(h, 2*jj);
    int g1 = c*16 + kmap(h, 2*jj + 1);
    unsigned int b0 = f2bf(w[((k*64 + f)*64 + g0)*3 + l]);
    unsigned int b1 = f2bf(w[((k*64 + f)*64 + g1)*3 + l]);
    pk[jj] = b0 | (b1 << 16);
  }
  *reinterpret_cast<uint4*>(wfrag + (size_t)slot * 8) = make_uint4(pk[0], pk[1], pk[2], pk[3]);
}

__global__ void bake_wh(const float* __restrict__ wxh, const float* __restrict__ wyh,
                        unsigned short* __restrict__ whfrag){
  int slot = blockIdx.x * 256 + threadIdx.x;      // < 2048
  int lane = slot & 63;
  int q = slot >> 6;
  int nt = q & 1; q >>= 1;
  int c  = q & 3; q >>= 2;
  int path = q & 1; int layer = q >> 1;
  const float* w = path ? wyh : wxh;
  int n = nt*32 + (lane & 31);
  int h = lane >> 5;
  unsigned int pk[4];
#pragma unroll
  for (int jj = 0; jj < 4; ++jj){
    int k0 = c*16 + kmap(h, 2*jj);
    int k1 = c*16 + kmap(h, 2*jj + 1);
    unsigned int b0 = f2bf(w[layer*4096 + k0*64 + n]);
    unsigned int b1 = f2bf(w[layer*4096 + k1*64 + n]);
    pk[jj] = b0 | (b1 << 16);
  }
  *reinterpret_cast<uint4*>(whfrag + (size_t)slot * 8) = make_uint4(pk[0], pk[1], pk[2], pk[3]);
}

__global__ void bake_wf(const float* __restrict__ wxf, const float* __restrict__ wyf,
                        unsigned short* __restrict__ wffrag){
  int slot = blockIdx.x * 256 + threadIdx.x;      // < 3072
  int lane = slot & 63;
  int q = slot >> 6;            // < 48
  int ntf = q % 6;
  int q2 = q / 6;
  int c = q2 & 3; int path = q2 >> 2;
  const float* w = path ? wyf : wxf;
  int n = ntf*32 + (lane & 31);
  int lw = n >> 6, fw = n & 63;
  int h = lane >> 5;
  unsigned int pk[4];
#pragma unroll
  for (int jj = 0; jj < 4; ++jj){
    int k0 = c*16 + kmap(h, 2*jj);
    int k1 = c*16 + kmap(h, 2*jj + 1);
    unsigned int b0 = f2bf(w[(lw*64 + fw)*64 + k0]);
    unsigned int b1 = f2bf(w[(lw*64 + fw)*64 + k1]);
    pk[jj] = b0 | (b1 << 16);
  }
  *reinterpret_cast<uint4*>(wffrag + (size_t)slot * 8) = make_uint4(pk[0], pk[1], pk[2], pk[3]);
}

// ---------------- main fused GEMM ----------------
// 4 classes: 0:{l=0,NCH4}, 1:{l=1,NCH4}, 2:{l=2,gh0,NCH2}, 3:{l=2,gh1,NCH2}
// Each WG: 128 points, 64 f-steps. xg held in registers across all steps.
// LDS: W ring[4][WN*4096 hw] ; A_img dbuf[2][4*NCH*512 hw]
template<int L, int NCH, int GH>
__device__ __forceinline__ void gemm_run(const float* __restrict__ x,
                                         const float* __restrict__ y,
                                         const unsigned short* __restrict__ wbase,
                                         float* __restrict__ mixp,
                                         char* lds, int mt_blk){
  constexpr int NS = 2*L + 1;
  constexpr int S0 = L*L;
  constexpr int WN = NCH/2;           // gl_lds16 ops per thread per step
  constexpr int NG = (NCH==4) ? 16 : 8;
  constexpr int RSTR = WN*4096;       // ring slot stride (halfwords)
  constexpr int ABUF = 4*NCH*512;     // A image buffer (halfwords)

  unsigned short* ring = (unsigned short*)lds;
  unsigned short* aimg = ring + 4*RSTR;

  const int t = threadIdx.x;
  const int pbase = mt_blk * 128;

  // A-gen role
  const int pp = t & 31;
  const int q  = (t >> 5) & 3;
  const int mt = t >> 7;
  const int c  = q & (NCH - 1);
  const int hh = (NCH==4) ? 0 : (q >> 1);
  const int p  = pbase + mt*32 + pp;
  const int gbase = GH*32 + c*16 + hh*8;

  // MFMA role
  const int w = t >> 6, lane = t & 63;
  const int wc = w & 1, wn = (w >> 1) & 1, wm = w >> 2;

  // ---- hoist xg (x * gate) into registers, reused for all 64 f-steps ----
  float xg[NG][NS];
  {
    const float* xr = x + (size_t)p * 576;
    const float* yr = y + (size_t)p * 576;
#pragma unroll
    for (int k = 0; k < NG; ++k){
      const float* xp = xr + (gbase + k)*9;
      const float* yp = yr + (gbase + k)*9;
      float x1 = xp[1], x2 = xp[2], x3 = xp[3];
      float y0 = yp[0], y1 = yp[1], y2 = yp[2], y3 = yp[3];
      float gate = (x2*y3 - x3*y2)*y0 + (x3*y1 - x1*y3)*y1 + (x1*y2 - x2*y1)*y2;
#pragma unroll
      for (int s = 0; s < NS; ++s) xg[k][s] = xp[S0 + s] * gate;
    }
  }

  // y stream (register ping-pong, 2-step prefetch)
  const float* ybase = y + (size_t)p * 576;
  float yc[NS], yn[NS];
#pragma unroll
  for (int s = 0; s < NS; ++s) yc[s] = ybase[S0 + s];
#pragma unroll
  for (int s = 0; s < NS; ++s) yn[s] = ybase[9 + S0 + s];

  // prologue: stage W(0), W(1)
#pragma unroll
  for (int ff = 0; ff < 2; ++ff){
    const unsigned short* srcp = wbase + ff*8192 + GH*4096 + t*8;
    unsigned short* dstp = ring + ff*RSTR + t*8;
    gl_lds16(srcp, dstp);
    if (NCH == 4) gl_lds16(srcp + 4096, dstp + 4096);
  }

  f32x16 acc00, acc01, acc10, acc11;
#pragma unroll
  for (int r = 0; r < 16; ++r){ acc00[r]=0.f; acc01[r]=0.f; acc10[r]=0.f; acc11[r]=0.f; }

#pragma unroll 1
  for (int f = 0; f < 64; ++f){
    // ---- issue W(f+2) into ring ----
    if (f + 2 < 64){
      const unsigned short* srcp = wbase + (f+2)*8192 + GH*4096 + t*8;
      unsigned short* dstp = ring + ((f+2)&3)*RSTR + t*8;
      gl_lds16(srcp, dstp);
      if (NCH == 4) gl_lds16(srcp + 4096, dstp + 4096);
    }
    // ---- A-gen(f): registers -> frag-order LDS image ----
    {
      float a[NG];
#pragma unroll
      for (int k = 0; k < NG; ++k){
        float v = yc[0] * xg[k][0];
#pragma unroll
        for (int s = 1; s < NS; ++s) v = fmaf(yc[s], xg[k][s], v);
        a[k] = v;
      }
      unsigned short* ab = aimg + (f&1)*ABUF + (mt*NCH + c)*512;
      if (NCH == 4){
        uint4 v0, v1;
        v0.x = pkbf(a[0],a[1]);   v0.y = pkbf(a[2],a[3]);
        v0.z = pkbf(a[8],a[9]);   v0.w = pkbf(a[10],a[11]);
        v1.x = pkbf(a[4],a[5]);   v1.y = pkbf(a[6],a[7]);
        v1.z = pkbf(a[12],a[13]); v1.w = pkbf(a[14],a[15]);
        *(uint4*)(ab + pp*8)        = v0;
        *(uint4*)(ab + (pp+32)*8)   = v1;
      } else {
        uint2 v0, v1;
        v0.x = pkbf(a[0],a[1]); v0.y = pkbf(a[2],a[3]);
        v1.x = pkbf(a[4],a[5]); v1.y = pkbf(a[6],a[7]);
        *(uint2*)(ab + pp*8 + hh*4)      = v0;
        *(uint2*)(ab + (pp+32)*8 + hh*4) = v1;
      }
    }
    // ---- rotate y regs, prefetch y(f+2) ----
#pragma unroll
    for (int s = 0; s < NS; ++s) yc[s] = yn[s];
    if (f + 2 < 64){
#pragma unroll
      for (int s = 0; s < NS; ++s) yn[s] = ybase[(f+2)*9 + S0 + s];
    }
    // ---- MFMA(f-1) ----
    if (f > 0){
      if (f >= 2 && f < 62){
        if constexpr (NCH == 4) asm volatile("s_waitcnt vmcnt(10)" ::: "memory");
        else                    asm volatile("s_waitcnt vmcnt(11)" ::: "memory");
      } else {
        if constexpr (NCH == 4) asm volatile("s_waitcnt vmcnt(4)" ::: "memory");
        else                    asm volatile("s_waitcnt vmcnt(5)" ::: "memory");
      }
      const unsigned short* ab = aimg + ((f-1)&1)*ABUF;
      const unsigned short* wb = ring + ((f-1)&3)*RSTR;
#pragma unroll
      for (int ci = 0; ci < NCH/2; ++ci){
        const int cc = (NCH==4) ? (wc*2 + ci) : wc;
        const unsigned short* a0p = ab + ((wm*2+0)*NCH + cc)*512 + lane*8;
        const unsigned short* a1p = a0p + NCH*512;
        const unsigned short* b0p = wb + (cc*4 + wn*2)*512 + lane*8;
        const unsigned short* b1p = b0p + 512;
        short8 av0 = *(const short8*)a0p, av1 = *(const short8*)a1p;
        short8 bv0 = *(const short8*)b0p, bv1 = *(const short8*)b1p;
        acc00 = __builtin_amdgcn_mfma_f32_32x32x16_bf16(av0, bv0, acc00, 0, 0, 0);
        acc01 = __builtin_amdgcn_mfma_f32_32x32x16_bf16(av0, bv1, acc01, 0, 0, 0);
        acc10 = __builtin_amdgcn_mfma_f32_32x32x16_bf16(av1, bv0, acc10, 0, 0, 0);
        acc11 = __builtin_amdgcn_mfma_f32_32x32x16_bf16(av1, bv1, acc11, 0, 0, 0);
      }
    }
    asm volatile("s_waitcnt lgkmcnt(0)" ::: "memory");
    __builtin_amdgcn_sched_barrier(0);
    __builtin_amdgcn_s_barrier();
  }
  // ---- tail MFMA(63) ----
  {
    asm volatile("s_waitcnt vmcnt(0)" ::: "memory");
    const unsigned short* ab = aimg + 1*ABUF;
    const unsigned short* wb = ring + 3*RSTR;
#pragma unroll
    for (int ci = 0; ci < NCH/2; ++ci){
      const int cc = (NCH==4) ? (wc*2 + ci) : wc;
      const unsigned short* a0p = ab + ((wm*2+0)*NCH + cc)*512 + lane*8;
      const unsigned short* a1p = a0p + NCH*512;
      const unsigned short* b0p = wb + (cc*4 + wn*2)*512 + lane*8;
      const unsigned short* b1p = b0p + 512;
      short8 av0 = *(const short8*)a0p, av1 = *(const short8*)a1p;
      short8 bv0 = *(const short8*)b0p, bv1 = *(const short8*)b1p;
      acc00 = __builtin_amdgcn_mfma_f32_32x32x16_bf16(av0, bv0, acc00, 0, 0, 0);
      acc01 = __builtin_amdgcn_mfma_f32_32x32x16_bf16(av0, bv1, acc01, 0, 0, 0);
      acc10 = __builtin_amdgcn_mfma_f32_32x32x16_bf16(av1, bv0, acc10, 0, 0, 0);
      acc11 = __builtin_amdgcn_mfma_f32_32x32x16_bf16(av1, bv1, acc11, 0, 0, 0);
    }
  }

  // ---- reduce over wc pairs, write mixp ----
  __syncthreads();
  float* red = (float*)lds;     // 4 slots x 4096 f32 = 64KB
  if (wc == 1){
    float* dst = red + (wm*2 + wn)*4096 + lane*16;
#pragma unroll
    for (int r = 0; r < 16; ++r){
      dst[r]        = acc00[r];
      dst[1024 + r] = acc01[r];
      dst[2048 + r] = acc10[r];
      dst[3072 + r] = acc11[r];
    }
  }
  __syncthreads();
  if (wc == 0){
    const float* sp = red + (wm*2 + wn)*4096 + lane*16;
#pragma unroll
    for (int r = 0; r < 16; ++r){
      acc00[r] += sp[r];
      acc01[r] += sp[1024 + r];
      acc10[r] += sp[2048 + r];
      acc11[r] += sp[3072 + r];
    }
    const int col = lane & 31, hb = lane >> 5;
#pragma unroll
    for (int r = 0; r < 16; ++r){
      int prow = (r & 3) + 8*(r >> 2) + 4*hb;
      float* m0 = mixp + (size_t)(pbase + (wm*2+0)*32 + prow)*128 + (wn*2)*32 + col;
      float* m1 = mixp + (size_t)(pbase + (wm*2+1)*32 + prow)*128 + (wn*2)*32 + col;
      m0[0]  = acc00[r];
      m0[32] = acc01[r];
      m1[0]  = acc10[r];
      m1[32] = acc11[r];
    }
  }
}

__global__ __launch_bounds__(512, 1)
void gemm_mix2(const float* __restrict__ x, const float* __restrict__ y,
               const unsigned short* __restrict__ wfrag, float* __restrict__ mixp){
  extern __shared__ char lds[];
  const int cls = blockIdx.x >> 6;
  const int mt  = blockIdx.x & 63;
  if (cls == 0)      gemm_run<0,4,0>(x, y, wfrag,             mixp,             lds, mt);
  else if (cls == 1) gemm_run<1,4,0>(x, y, wfrag + 64*8192,   mixp + 1048576,   lds, mt);
  else if (cls == 2) gemm_run<2,2,0>(x, y, wfrag + 128*8192,  mixp + 2097152,   lds, mt);
  else               gemm_run<2,2,1>(x, y, wfrag + 128*8192,  mixp + 3145728,   lds, mt);
}

// ---------------- MLP + final einsum + epilogue ----------------
__global__ __launch_bounds__(256, 1)
void mlp_final(const float* __restrict__ x, const float* __restrict__ y,
               const unsigned short* __restrict__ whfrag,
               const unsigned short* __restrict__ wffrag,
               const float* __restrict__ mixp, float* __restrict__ out){
  extern __shared__ char ldsm[];
  unsigned short* hw = (unsigned short*)ldsm;
  const int t = threadIdx.x;
  const long pbase = (long)blockIdx.x * 32;

  {  // load mix = sum of 4 partials -> act buf0 (bf16)
    int p = t >> 3, n0 = (t & 7) * 16;
    const float* src = mixp + (pbase + p)*128 + n0;
    int path = n0 >> 6, nn = n0 & 63;
    unsigned short* dst = hw + (path*2)*2176 + p*68 + nn;
#pragma unroll
    for (int q2 = 0; q2 < 16; ++q2){
      float v = src[q2] + src[q2 + 1048576] + src[q2 + 2097152] + src[q2 + 3145728];
      dst[q2] = f2bf(v);
    }
  }
  __syncthreads();

  const int w = t >> 6, lane = t & 63;
  const int path = w >> 1, ntw = w & 1;
  const int prow = lane & 31, h = lane >> 5;
  int cur = 0;

#pragma unroll
  for (int layer = 0; layer < 2; ++layer){
    const unsigned short* act = hw + (path*2 + cur)*2176;
    f32x16 acc;
#pragma unroll
    for (int r = 0; r < 16; ++r) acc[r] = 0.f;
#pragma unroll
    for (int c = 0; c < 4; ++c){
      int ab = prow*68 + c*16 + 4*h;
      ushort4 lo = *(const ushort4*)&act[ab];
      ushort4 hi = *(const ushort4*)&act[ab + 8];
      short8 av; av[0]=lo.x; av[1]=lo.y; av[2]=lo.z; av[3]=lo.w;
      av[4]=hi.x; av[5]=hi.y; av[6]=hi.z; av[7]=hi.w;
      short8 bv = *(const short8*)(whfrag + ((((layer*2 + path)*4 + c)*2 + ntw)*512 + lane*8));
      acc = __builtin_amdgcn_mfma_f32_32x32x16_bf16(av, bv, acc, 0, 0, 0);
    }
    unsigned short* nact = hw + (path*2 + (cur ^ 1))*2176;
#pragma unroll
    for (int r = 0; r < 16; ++r){
      int p = (r & 3) + 8*(r >> 2) + 4*h;
      nact[p*68 + ntw*32 + prow] = f2bf(tanh_fast(acc[r]));
    }
    cur ^= 1;
    __syncthreads();
  }

  {  // final einsum: o[p][n=l*64+f], N=192 -> each wave 3 n-tiles
    const unsigned short* act = hw + (path*2 + cur)*2176;
    unsigned short* ob = hw + 8704 + path*6272;
#pragma unroll
    for (int e = 0; e < 3; ++e){
      int ntf = ntw*3 + e;
      f32x16 acc;
#pragma unroll
      for (int r = 0; r < 16; ++r) acc[r] = 0.f;
#pragma unroll
      for (int c = 0; c < 4; ++c){
        int ab = prow*68 + c*16 + 4*h;
        ushort4 lo = *(const ushort4*)&act[ab];
        ushort4 hi = *(const ushort4*)&act[ab + 8];
        short8 av; av[0]=lo.x; av[1]=lo.y; av[2]=lo.z; av[3]=lo.w;
        av[4]=hi.x; av[5]=hi.y; av[6]=hi.z; av[7]=hi.w;
        short8 bv = *(const short8*)(wffrag + (((path*4 + c)*6 + ntf)*512 + lane*8));
        acc = __builtin_amdgcn_mfma_f32_32x32x16_bf16(av, bv, acc, 0, 0, 0);
      }
#pragma unroll
      for (int r = 0; r < 16; ++r){
        int p = (r & 3) + 8*(r >> 2) + 4*h;
        ob[p*196 + ntf*32 + prow] = f2bf(tanh_fast(acc[r]));
      }
    }
  }
  __syncthreads();

  const unsigned short* oxb = hw + 8704;
  const unsigned short* oyb = hw + 8704 + 6272;
#pragma unroll 1
  for (int rep = 0; rep < 8; ++rep){
    int idx = t + rep*256;
    int p = idx >> 6, fq = idx & 63;
    const float* xr = x + ((pbase + p)*64 + fq)*9;
    const float* yr = y + ((pbase + p)*64 + fq)*9;
    float xv[9], yv[9];
#pragma unroll
    for (int s = 0; s < 9; ++s){ xv[s] = xr[s]; yv[s] = yr[s]; }
    float c0 = xv[2]*yv[3] - xv[3]*yv[2];
    float c1 = xv[3]*yv[1] - xv[1]*yv[3];
    float c2 = xv[1]*yv[2] - xv[2]*yv[1];
    float gate = c0*yv[0] + c1*yv[1] + c2*yv[2];
    float ox0 = bf2f(oxb[p*196 + fq]);
    float ox1 = bf2f(oxb[p*196 + 64 + fq]);
    float ox2 = bf2f(oxb[p*196 + 128 + fq]);
    float oy0 = bf2f(oyb[p*196 + fq]);
    float oy1 = bf2f(oyb[p*196 + 64 + fq]);
    float oy2 = bf2f(oyb[p*196 + 128 + fq]);
    float* orow = out + ((pbase + p)*64 + fq)*9;
    orow[0] = ox0*xv[0]*gate + oy0*yv[0];
#pragma unroll
    for (int s = 1; s < 4; ++s) orow[s] = ox1*xv[s]*gate + oy1*yv[s];
#pragma unroll
    for (int s = 4; s < 9; ++s) orow[s] = ox2*xv[s]*gate + oy2*yv[s];
  }
}

extern "C" void kernel_launch(void* const* d_in, const int* in_sizes, int n_in,
                              void* d_out, int out_size, void* d_ws, size_t ws_size,
                              hipStream_t stream){
  (void)in_sizes; (void)n_in; (void)out_size; (void)ws_size;
  const float* x   = (const float*)d_in[0];
  const float* y   = (const float*)d_in[1];
  const float* wx0 = (const float*)d_in[2];
  const float* wy0 = (const float*)d_in[3];
  const float* wxh = (const float*)d_in[4];
  const float* wyh = (const float*)d_in[5];
  const float* wxf = (const float*)d_in[6];
  const float* wyf = (const float*)d_in[7];
  float* out = (float*)d_out;
  char* ws = (char*)d_ws;
  unsigned short* wfrag  = (unsigned short*)(ws);             // 3,145,728 B
  unsigned short* whfrag = (unsigned short*)(ws + 3145728);   //    32,768 B
  unsigned short* wffrag = (unsigned short*)(ws + 3178496);   //    49,152 B
  float* mixp = (float*)(ws + 3227648);                       // 4 x 4,194,304 B

  (void)hipFuncSetAttribute((const void*)gemm_mix2,
        hipFuncAttributeMaxDynamicSharedMemorySize, 98304);
  (void)hipFuncSetAttribute((const void*)mlp_final,
        hipFuncAttributeMaxDynamicSharedMemorySize, 43520);

  hipLaunchKernelGGL(bake_w0, dim3(768), dim3(256), 0, stream, wx0, wy0, wfrag);
  hipLaunchKernelGGL(bake_wh, dim3(8),   dim3(256), 0, stream, wxh, wyh, whfrag);
  hipLaunchKernelGGL(bake_wf, dim3(12),  dim3(256), 0, stream, wxf, wyf, wffrag);
  hipLaunchKernelGGL(gemm_mix2, dim3(256), dim3(512), 98304, stream, x, y, wfrag, mixp);
  hipLaunchKernelGGL(mlp_final, dim3(256), dim3(256), 42496, stream, x, y, whfrag, wffrag, mixp, out);
}